// Round 17
// baseline (410.558 us; speedup 1.0000x reference)
//
#include <hip/hip_runtime.h>

// SPModel_6846177870356: y = x@W^T + all2all permute. M=28160, N=K=2048.
// Inputs FP32 (harness-upcast fp16), output FP32.
// Round 17 = R16 (BM=256,BN=128 -> 1760 blocks, 2 phases/tile) with the
// CORRECTED gate ledger (R16 raced: no prologue gate + gates one phase late).
// Invariant: each phase's vmcnt gate certifies the NEXT phase's pre-barrier
// reads. Prologue: stage {A0,B,A1}, VM(2);BAR (certify A0,B; leave A1 x2).
// p0: read A0(t),B(t); stage A0,B(t+1); VM(4) [certify A1(t)]; BAR; LGKM0;
//     16 MFMA; BAR.
// p1: read A1(t);      stage A1(t+1);   VM(2) [certify A0,B(t+1)]; BAR; ...
// Pre-swizzled f16 globals (R9), XOR ds_read (T2), setprio (T5), XCD swizzle.

typedef _Float16 f16;
typedef _Float16 f16x2 __attribute__((ext_vector_type(2)));
typedef _Float16 f16x8 __attribute__((ext_vector_type(8)));
typedef float    f32x4 __attribute__((ext_vector_type(4)));

#define GPTR(p) ((const __attribute__((address_space(1))) void*)(p))
#define LPTR(p) ((__attribute__((address_space(3))) void*)(p))

constexpr int Mdim = 28160;   // 8*44*80
constexpr int Ndim = 2048;
constexpr int Kdim = 2048;
constexpr int BM = 256, BN = 128, BK = 64;
constexpr int NWG = (Mdim / BM) * (Ndim / BN);  // 110*16 = 1760 (%8==0)
constexpr int NT  = Kdim / BK;                  // 32
constexpr size_t XS_ELEMS = (size_t)Mdim * Kdim;
constexpr size_t WS_ELEMS = (size_t)Ndim * Kdim;
constexpr size_t WS_NEED  = (XS_ELEMS + WS_ELEMS) * sizeof(f16);

__device__ __forceinline__ f16x8 pack8(const f32x4& lo, const f32x4& hi) {
    f16x2 p0 = __builtin_bit_cast(f16x2, __builtin_amdgcn_cvt_pkrtz(lo[0], lo[1]));
    f16x2 p1 = __builtin_bit_cast(f16x2, __builtin_amdgcn_cvt_pkrtz(lo[2], lo[3]));
    f16x2 p2 = __builtin_bit_cast(f16x2, __builtin_amdgcn_cvt_pkrtz(hi[0], hi[1]));
    f16x2 p3 = __builtin_bit_cast(f16x2, __builtin_amdgcn_cvt_pkrtz(hi[2], hi[3]));
    return (f16x8){p0[0], p0[1], p1[0], p1[1], p2[0], p2[1], p3[0], p3[1]};
}

// f32 [rows x 2048] -> f16 pre-swizzled: dst[m][(k8 ^ (m&7))*8] (R9-verified).
__global__ __launch_bounds__(256)
void convert_kernel(const float* __restrict__ src, f16* __restrict__ dst) {
    const int idx = blockIdx.x * 256 + threadIdx.x;
    const int m   = idx >> 8;
    const int k8  = idx & 255;
    const int k8s = k8 ^ (m & 7);
    const float* p = src + (size_t)m * Kdim + k8 * 8;
    f32x4 lo = *(const f32x4*)p;
    f32x4 hi = *(const f32x4*)(p + 4);
    *(f16x8*)(dst + (size_t)m * Kdim + k8s * 8) = pack8(lo, hi);
}

// swizzled LDS read: row stride 128B, byte ^= (row&7)<<4 (0 conflicts)
__device__ __forceinline__ f16x8 lds_frag(const f16* base, int r, int kc) {
    const int b = ((r * BK + kc) * 2) ^ ((r & 7) << 4);
    return *(const f16x8*)((const char*)base + b);
}

__global__ __launch_bounds__(512, 2)
void gemm_a2a_kernel(const f16* __restrict__ Xs, const f16* __restrict__ Ws,
                     float* __restrict__ out) {
    __shared__ f16 sA[2][BM * BK];   // 32 KiB each (swizzled image)
    __shared__ f16 sB[2][BN * BK];   // 16 KiB each  (total 96 KiB)

    const int tid  = threadIdx.x;
    const int lane = tid & 63;
    const int wid  = tid >> 6;
    const int wm   = wid >> 2;          // 0..1 -> 128 M-rows
    const int wn   = wid & 3;           // 0..3 -> 32 N-cols

    const int cpx  = NWG >> 3;                       // XCD-bijective swizzle
    const int tile = (blockIdx.x & 7) * cpx + (blockIdx.x >> 3);
    const int bn   = tile & 15;                      // 16 N-tiles
    const int bm   = tile >> 4;
    const int row0 = bm * BM;
    const int col0 = bn * BN;

    const int lr = lane & 15;
    const int kq = (lane >> 4) * 8;

    f32x4 acc[8][2] = {};

    // staging: A_u0 = rows {0-63}∪{128-191}; A_u1 = {64-127}∪{192-255};
    // B = rows 0-127. Two gload_lds per unit per thread-group issue.
    const f16* srcA[2][2]; const f16* srcB[2];
    int dstA[2][2], dstB[2];
    {
        const int rl = tid >> 3;            // 0..63
        const int ka = (tid & 7) * 8;       // pre-swizzled k offset
#pragma unroll
        for (int u = 0; u < 2; ++u)
#pragma unroll
            for (int g = 0; g < 2; ++g) {
                const int ra = u * 64 + g * 128 + rl;
                srcA[u][g] = Xs + (size_t)(row0 + ra) * Kdim + ka;
                dstA[u][g] = (ra * 8 + (tid & 7)) * 8;
            }
#pragma unroll
        for (int g = 0; g < 2; ++g) {
            const int rb = g * 64 + rl;
            srcB[g] = Ws + (size_t)(col0 + rb) * Kdim + ka;
            dstB[g] = (rb * 8 + (tid & 7)) * 8;
        }
    }

#define STAGE_A(T, D, U)                                                     \
    do {                                                                     \
        __builtin_amdgcn_global_load_lds(GPTR(srcA[U][0] + (T) * BK),        \
            LPTR(&sA[D][dstA[U][0]]), 16, 0, 0);                             \
        __builtin_amdgcn_global_load_lds(GPTR(srcA[U][1] + (T) * BK),        \
            LPTR(&sA[D][dstA[U][1]]), 16, 0, 0);                             \
    } while (0)
#define STAGE_B(T, D)                                                        \
    do {                                                                     \
        __builtin_amdgcn_global_load_lds(GPTR(srcB[0] + (T) * BK),           \
            LPTR(&sB[D][dstB[0]]), 16, 0, 0);                                \
        __builtin_amdgcn_global_load_lds(GPTR(srcB[1] + (T) * BK),           \
            LPTR(&sB[D][dstB[1]]), 16, 0, 0);                                \
    } while (0)

    f16x8 Af[4][2], Bf[2][2];
    auto readA = [&](const f16* base, int qm) {
#pragma unroll
        for (int f = 0; f < 4; ++f)
#pragma unroll
            for (int kk = 0; kk < 2; ++kk)
                Af[f][kk] = lds_frag(base, wm * 128 + qm * 64 + f * 16 + lr,
                                     kk * 32 + kq);
    };
    auto readB = [&](const f16* base) {
#pragma unroll
        for (int g = 0; g < 2; ++g)
#pragma unroll
            for (int kk = 0; kk < 2; ++kk)
                Bf[g][kk] = lds_frag(base, wn * 32 + g * 16 + lr,
                                     kk * 32 + kq);
    };

#define MFMA16(QM)                                                           \
    do {                                                                     \
        __builtin_amdgcn_s_setprio(1);                                       \
        _Pragma("unroll")                                                    \
        for (int kk = 0; kk < 2; ++kk)                                       \
            _Pragma("unroll")                                                \
            for (int f = 0; f < 4; ++f)                                      \
                _Pragma("unroll")                                            \
                for (int g = 0; g < 2; ++g)                                  \
                    acc[(QM)*4 + f][g] =                                     \
                        __builtin_amdgcn_mfma_f32_16x16x32_f16(              \
                            Af[f][kk], Bf[g][kk],                            \
                            acc[(QM)*4 + f][g], 0, 0, 0);                    \
        __builtin_amdgcn_s_setprio(0);                                       \
    } while (0)

#define VM(N)   asm volatile("s_waitcnt vmcnt(" #N ")" ::: "memory")
#define BAR()   __builtin_amdgcn_s_barrier()
#define LGKM0() do { asm volatile("s_waitcnt lgkmcnt(0)" ::: "memory");      \
                     __builtin_amdgcn_sched_barrier(0); } while (0)

    // Prologue: stage {A_u0, B, A_u1}(0) = 6 outstanding; certify A_u0,B.
    STAGE_A(0, 0, 0); STAGE_B(0, 0); STAGE_A(0, 0, 1);
    VM(2); BAR();                              // leaves [A_u1(0) x2]

    for (int t = 0; t < NT - 1; ++t) {
        const int d  = t & 1;
        const int dn = d ^ 1;
        const int tn = t + 1;
        // p0: qm=0 — A_u0(t),B(t) certified by previous phase's gate
        readA(sA[d], 0); readB(sB[d]);
        STAGE_A(tn, dn, 0); STAGE_B(tn, dn);   // 2 -> 6 outstanding
        VM(4); BAR(); LGKM0();                 // certifies A_u1(t)
        MFMA16(0);
        BAR();
        // p1: qm=1 — A_u1(t) certified
        readA(sA[d], 1);                       // B held in regs
        STAGE_A(tn, dn, 1);                    // 4 -> 6 outstanding
        VM(2); BAR(); LGKM0();                 // certifies A_u0,B(t+1)
        MFMA16(1);
        BAR();
    }

    // Peeled last tile: invariant [A_u1(NT-1) x2] outstanding.
    {
        const int d = (NT - 1) & 1;
        readA(sA[d], 0); readB(sB[d]);         // certified by last loop gate
        VM(0); BAR(); LGKM0();                 // certifies A_u1(NT-1)
        MFMA16(0);
        BAR();
        readA(sA[d], 1);
        LGKM0();
        MFMA16(1);
    }

    // Epilogue: C/D col=lane&15 (n), row=(lane>>4)*4+j (m); fused all2all:
    // out[(n>>8)*M*256 + m*256 + (n&255)], f32 stores.
    const int R0 = row0 + wm * 128;
    const int C0 = col0 + wn * 32;
#pragma unroll
    for (int mi = 0; mi < 8; ++mi)
#pragma unroll
        for (int ni = 0; ni < 2; ++ni) {
            const int n     = C0 + ni * 16 + (lane & 15);
            const int rbase = R0 + mi * 16 + (lane >> 4) * 4;
            const size_t obase = (size_t)(n >> 8) * ((size_t)Mdim * 256) + (n & 255);
#pragma unroll
            for (int j = 0; j < 4; ++j)
                out[obase + (size_t)(rbase + j) * 256] = acc[mi][ni][j];
        }
}

// ---- Fallback (R7-verified): direct-f32 reg-staged dbuf 128^2 kernel ----
constexpr int FBM = 128, FBK = 64;
constexpr int FNWG = (Mdim / FBM) * (Ndim / FBM);
__global__ __launch_bounds__(256)
void gemm_a2a_f32_kernel(const float* __restrict__ X, const float* __restrict__ W,
                         float* __restrict__ out) {
    __shared__ f16 sA[2][FBM * FBK];
    __shared__ f16 sB[2][FBM * FBK];
    const int tid  = threadIdx.x;
    const int lane = tid & 63;
    const int wid  = tid >> 6;
    const int wr   = wid >> 1;
    const int wc   = wid & 1;
    const int cpx  = FNWG >> 3;
    const int tile = (blockIdx.x & 7) * cpx + (blockIdx.x >> 3);
    const int bn   = tile & 15;
    const int bm   = tile >> 4;
    const int row0 = bm * FBM;
    const int col0 = bn * FBM;
    f32x4 acc[4][4] = {};
    f32x4 ra[8], rb[8];
    auto load_tile = [&](int t) {
#pragma unroll
        for (int i = 0; i < 4; ++i) {
            const int c8 = i * 256 + tid;
            const int r  = c8 >> 3;
            const int cc = (c8 & 7) * 8;
            const float* pa = X + (size_t)(row0 + r) * Kdim + t * FBK + cc;
            const float* pb = W + (size_t)(col0 + r) * Kdim + t * FBK + cc;
            ra[2*i] = *(const f32x4*)pa; ra[2*i+1] = *(const f32x4*)(pa + 4);
            rb[2*i] = *(const f32x4*)pb; rb[2*i+1] = *(const f32x4*)(pb + 4);
        }
    };
    int cur = 0;
    load_tile(0);
    for (int t = 0; t < Kdim / FBK; ++t) {
#pragma unroll
        for (int i = 0; i < 4; ++i) {
            const int c8 = i * 256 + tid;
            const int sb = (c8 * 16) ^ (((c8 >> 3) & 7) << 4);
            *(f16x8*)((char*)sA[cur] + sb) = pack8(ra[2*i], ra[2*i+1]);
            *(f16x8*)((char*)sB[cur] + sb) = pack8(rb[2*i], rb[2*i+1]);
        }
        if (t + 1 < Kdim / FBK) load_tile(t + 1);
        __syncthreads();
        const f16* Ab = sA[cur];
        const f16* Bb = sB[cur];
#pragma unroll
        for (int kk = 0; kk < FBK; kk += 32) {
            const int kc = kk + (lane >> 4) * 8;
            f16x8 af[4], bfr[4];
#pragma unroll
            for (int f = 0; f < 4; ++f) {
                const int rowA = wr * 64 + f * 16 + (lane & 15);
                af[f] = *(const f16x8*)((const char*)Ab + (((rowA * FBK + kc) * 2) ^ ((rowA & 7) << 4)));
                const int rowB = wc * 64 + f * 16 + (lane & 15);
                bfr[f] = *(const f16x8*)((const char*)Bb + (((rowB * FBK + kc) * 2) ^ ((rowB & 7) << 4)));
            }
#pragma unroll
            for (int mi = 0; mi < 4; ++mi)
#pragma unroll
                for (int ni = 0; ni < 4; ++ni)
                    acc[mi][ni] = __builtin_amdgcn_mfma_f32_16x16x32_f16(
                        af[mi], bfr[ni], acc[mi][ni], 0, 0, 0);
        }
        cur ^= 1;
    }
#pragma unroll
    for (int mi = 0; mi < 4; ++mi)
#pragma unroll
        for (int ni = 0; ni < 4; ++ni) {
            const int n     = col0 + wc * 64 + ni * 16 + (lane & 15);
            const int rbase = row0 + wr * 64 + mi * 16 + (lane >> 4) * 4;
            const size_t obase = (size_t)(n >> 8) * ((size_t)Mdim * 256) + (n & 255);
#pragma unroll
            for (int j = 0; j < 4; ++j)
                out[obase + (size_t)(rbase + j) * 256] = acc[mi][ni][j];
        }
}

extern "C" void kernel_launch(void* const* d_in, const int* in_sizes, int n_in,
                              void* d_out, int out_size, void* d_ws, size_t ws_size,
                              hipStream_t stream) {
    const float* X = (const float*)d_in[0];
    const float* W = (const float*)d_in[1];
    float* out     = (float*)d_out;
    if (ws_size >= WS_NEED) {
        f16* Xs = (f16*)d_ws;
        f16* Ws = Xs + XS_ELEMS;
        hipLaunchKernelGGL(convert_kernel, dim3((int)(XS_ELEMS / 8 / 256)), dim3(256),
                           0, stream, X, Xs);
        hipLaunchKernelGGL(convert_kernel, dim3((int)(WS_ELEMS / 8 / 256)), dim3(256),
                           0, stream, W, Ws);
        hipLaunchKernelGGL(gemm_a2a_kernel, dim3(NWG), dim3(512), 0, stream, Xs, Ws, out);
    } else {
        hipLaunchKernelGGL(gemm_a2a_f32_kernel, dim3(FNWG), dim3(256), 0, stream, X, W, out);
    }
}